// Round 2
// baseline (10212.770 us; speedup 1.0000x reference)
//
#include <hip/hip_runtime.h>

// ---------------------------------------------------------------------------
// Teacher_model_7464653160858: embed+BN -> 3x GRU(1024, reset_after) -> dense+softmax
// B=64, T=512, E=256, U=1024, V=512.
//
// R5: R4 + XCD-PAIR PLACEMENT. R4 post-mortem: pipeline overlapped but each
// layer's recurrence tripled to ~19us/step -- the h-exchange is bound by the
// MALL miss-service rate (~190 GB/s aggregate, Little's law on 64B lines),
// and R4's per-step L2-miss traffic tripled vs R3 (each slab fetched into
// ~4 XCD L2s under round-robin dispatch).
//  - Launch 256 WGs; XCD slot = blockIdx%8 (MI355X round-robin dispatch).
//    Slots {0,1}->layer0, {2,3}->layer1, {4,5}->layer2, {6,7} exit.
//    Each layer's 64 WGs then occupy ONE XCD PAIR: per-step slab fetch
//    drops from ~5 slab-copies/step to ~2.5 (own pair + next-layer pair).
//  - Pure scheduling hint: if the %8 mapping guess is wrong, behavior
//    degenerates to R4's mixed placement (correctness unaffected).
//  - Everything else identical to R4 (verified): register-resident weights,
//    sc0sc1 write-through slabs, plain flag-gated reads, monotonic flags,
//    lane-parallel relaxed-atomic polls, R=512/256 ring w/ epoch fences.
// ---------------------------------------------------------------------------

typedef short bf16x8 __attribute__((ext_vector_type(8)));
typedef float f32x4 __attribute__((ext_vector_type(4)));
typedef unsigned short ushort_t;

#define MFMA16(a, b, c) __builtin_amdgcn_mfma_f32_16x16x32_bf16((a), (b), (c), 0, 0, 0)

#define SLAB 65536        // elems per h slab: 128 u8-groups * 64 b * 8 (128 KB)

__device__ __forceinline__ float bf2f(ushort_t h) {
    return __uint_as_float(((unsigned)h) << 16);
}
__device__ __forceinline__ ushort_t f2bf(float f) {
    unsigned u = __float_as_uint(f);
    u += 0x7FFFu + ((u >> 16) & 1u);   // RNE
    return (ushort_t)(u >> 16);
}
__device__ __forceinline__ float sigmf(float x) { return 1.f / (1.f + __expf(-x)); }
__device__ __forceinline__ float tanhfast(float x) {
    float e = __expf(2.f * x);
    return 1.f - 2.f / (e + 1.f);
}

// ---------------------------------------------------------------------------
// pack: W[K][3072] fp32 -> WT[3072][K] bf16 (transpose). grid (K/64, 48).
// ---------------------------------------------------------------------------
__global__ __launch_bounds__(256, 1) void pack_w(
    const float* __restrict__ W, ushort_t* __restrict__ WT, int K)
{
    __shared__ ushort_t tile[64][72];
    const int kt0 = blockIdx.x * 64;
    const int ct0 = blockIdx.y * 64;
    const int tx = threadIdx.x & 63;
    const int ty = threadIdx.x >> 6;
#pragma unroll
    for (int i = 0; i < 16; ++i) {
        int k = kt0 + ty * 16 + i;
        tile[ty * 16 + i][tx] = f2bf(W[(size_t)k * 3072 + ct0 + tx]);
    }
    __syncthreads();
#pragma unroll
    for (int i = 0; i < 16; ++i) {
        int c = ct0 + ty * 16 + i;
        WT[(size_t)c * K + kt0 + tx] = tile[tx][ty * 16 + i];
    }
}

// ---------------------------------------------------------------------------
// BN-folded embedding table (512x256 bf16)
// ---------------------------------------------------------------------------
__global__ __launch_bounds__(256, 1) void embed_bn(
    const float* __restrict__ emb,
    const float* __restrict__ gamma, const float* __restrict__ beta,
    const float* __restrict__ mean, const float* __restrict__ var,
    ushort_t* __restrict__ embBN)
{
    const int idx = blockIdx.x * 256 + threadIdx.x;
    const int e = idx & 255;
    const float sc = gamma[e] * rsqrtf(var[e] + 1e-3f);
    const float sh = beta[e] - mean[e] * sc;
    embBN[idx] = f2bf(fmaf(emb[idx], sc, sh));
}

// ---------------------------------------------------------------------------
// gru_run: one GRU layer, 64 WGs x 256 thr, all 512 steps in one dispatch.
// XKC = x-part K-chunks (8 for E=256 embedding input, 32 for U=1024 h input).
// Wave roles (4-way K-split over combined K = XKC+32 chunks of 32):
//   XKC=8 : w0 = x(8 kc);  w1/w2/w3 = h(11/11/10 kc)
//   XKC=32: w0/w1 = x(16/16 kc); w2/w3 = h(16/16 kc)
// ---------------------------------------------------------------------------
template<int XKC, bool EMB>
__device__ __forceinline__ void gru_run(
    const int* __restrict__ tokens,
    const ushort_t* __restrict__ embBN,
    const ushort_t* __restrict__ WkT,      // [3072][XKC*32]
    const ushort_t* __restrict__ WrT,      // [3072][1024]
    const float* __restrict__ gb,          // [2][3072] flat
    ushort_t* __restrict__ hxOwn,          // own slab ring base
    const ushort_t* __restrict__ hxPrev,   // prev-layer ring base (null if EMB)
    float* __restrict__ Hf,                // non-null on last layer only
    unsigned* __restrict__ flags,          // [3*64]
    const int layer, const int lwg, const int R,
    f32x4* __restrict__ ldsRed)
{
    const int tid  = threadIdx.x;
    const int lane = tid & 63;
    const int w    = tid >> 6;
    const int n    = lane & 15, quad = lane >> 4;
    const int u_   = lwg * 16 + n;

    const bool ISX = (XKC == 8) ? (w == 0) : (w < 2);
    const int  CNT = (XKC == 8) ? ((w == 0) ? 8 : ((w == 3) ? 10 : 11)) : 16;
    const int  BASE = (XKC == 8) ? ((w == 0) ? 0 : 11 * (w - 1))
                                 : (ISX ? (w * 16) : ((w - 2) * 16));
    const int  KROW = ISX ? (EMB ? 256 : 1024) : 1024;
    const ushort_t* WT = ISX ? WkT : WrT;

    // once per dispatch: drop stale/poisoned L2 lines from prior launches
    __threadfence();

    // ---- preload weight B-fragments to registers (static-indexed) ----
    bf16x8 wf[16][3];
#pragma unroll
    for (int i = 0; i < 16; ++i)
        if (i < CNT) {
            const int kc = BASE + i;
#pragma unroll
            for (int g = 0; g < 3; ++g)
                wf[i][g] = *(const bf16x8*)(WT + (size_t)(g * 1024 + u_) * KROW
                                            + kc * 32 + quad * 8);
        }

    const float bzz = gb[u_]        + gb[3072 + u_];
    const float brr = gb[1024 + u_] + gb[4096 + u_];
    const float bxh = gb[2048 + u_];
    const float brh = gb[5120 + u_];

    float hcur[4] = {0.f, 0.f, 0.f, 0.f};
    const int rowBase = w * 16 + quad * 4;   // this wave gates batch rows rowBase..+3

    for (int s = 0; s < 512; ++s) {
        // ---- 1. wave0 polls: own h_{s-1}, prev-layer h_s, next-layer ring slack
        if (w == 0) {
            const unsigned ownT = (unsigned)s;
            const unsigned prvT = (layer > 0) ? (unsigned)(s + 1) : 0u;
            const unsigned nxtT = (layer < 2 && s >= R) ? (unsigned)(s - R + 1) : 0u;
            if (ownT | prvT | nxtT) {
                const unsigned* fO = flags + layer * 64 + lane;
                const unsigned* fP = flags + (layer - 1) * 64 + lane;
                const unsigned* fN = flags + (layer + 1) * 64 + lane;
                while (true) {
                    bool ok = true;
                    if (ownT) ok &= (__ballot(__hip_atomic_load(fO, __ATOMIC_RELAXED,
                                     __HIP_MEMORY_SCOPE_AGENT) >= ownT) == ~0ull);
                    if (prvT) ok &= (__ballot(__hip_atomic_load(fP, __ATOMIC_RELAXED,
                                     __HIP_MEMORY_SCOPE_AGENT) >= prvT) == ~0ull);
                    if (nxtT) ok &= (__ballot(__hip_atomic_load(fN, __ATOMIC_RELAXED,
                                     __HIP_MEMORY_SCOPE_AGENT) >= nxtT) == ~0ull);
                    if (ok) break;
                    __builtin_amdgcn_s_sleep(1);
                }
            }
        }
        __syncthreads();
        asm volatile("" ::: "memory");        // no load hoisting above the poll
        // epoch fence: drop L2 copies of ring addresses about to be re-read
        if (R == 256 && (s == 256 || s == 511)) __threadfence();

        const ushort_t* slabO = hxOwn + (size_t)((s - 1) & (R - 1)) * SLAB;

        // ---- 2. MFMA: this wave's K-slice (weights in regs, h from slabs)
        f32x4 acc[4][3] = {};
        if (ISX) {
            if (EMB) {
                int tk[4];
#pragma unroll
                for (int rt = 0; rt < 4; ++rt)
                    tk[rt] = tokens[(rt * 16 + n) * 512 + s] * 256;
#pragma unroll
                for (int i = 0; i < 16; ++i)
                    if (i < CNT) {
                        const int kc = BASE + i;
                        bf16x8 a[4];
#pragma unroll
                        for (int rt = 0; rt < 4; ++rt)
                            a[rt] = *(const bf16x8*)(embBN + (size_t)tk[rt]
                                                     + kc * 32 + quad * 8);
#pragma unroll
                        for (int rt = 0; rt < 4; ++rt)
#pragma unroll
                            for (int g = 0; g < 3; ++g)
                                acc[rt][g] = MFMA16(a[rt], wf[i][g], acc[rt][g]);
                    }
            } else {
                const ushort_t* slabP = hxPrev + (size_t)(s & (R - 1)) * SLAB;
#pragma unroll
                for (int i = 0; i < 16; ++i)
                    if (i < CNT) {
                        const int kc = BASE + i;
                        bf16x8 a[4];
#pragma unroll
                        for (int rt = 0; rt < 4; ++rt)
                            a[rt] = *(const bf16x8*)(slabP +
                                     ((kc * 4 + quad) * 64 + rt * 16 + n) * 8);
#pragma unroll
                        for (int rt = 0; rt < 4; ++rt)
#pragma unroll
                            for (int g = 0; g < 3; ++g)
                                acc[rt][g] = MFMA16(a[rt], wf[i][g], acc[rt][g]);
                    }
            }
        } else if (s > 0) {                   // h_0 = 0: skip at s==0
#pragma unroll
            for (int i = 0; i < 16; ++i)
                if (i < CNT) {
                    const int kc = BASE + i;
                    bf16x8 a[4];
#pragma unroll
                    for (int rt = 0; rt < 4; ++rt)
                        a[rt] = *(const bf16x8*)(slabO +
                                 ((kc * 4 + quad) * 64 + rt * 16 + n) * 8);
#pragma unroll
                    for (int rt = 0; rt < 4; ++rt)
#pragma unroll
                        for (int g = 0; g < 3; ++g)
                            acc[rt][g] = MFMA16(a[rt], wf[i][g], acc[rt][g]);
                }
        }

        // ---- 3. cross-wave K-reduce via LDS
#pragma unroll
        for (int rt = 0; rt < 4; ++rt)
#pragma unroll
            for (int g = 0; g < 3; ++g)
                ldsRed[((w * 4 + rt) * 3 + g) * 64 + lane] = acc[rt][g];
        __syncthreads();

        f32x4 sz = {}, sr = {}, sxh = {}, srh = {};
#pragma unroll
        for (int wp = 0; wp < 4; ++wp) {
            const bool xw = (XKC == 8) ? (wp == 0) : (wp < 2);
            sz += ldsRed[((wp * 4 + w) * 3 + 0) * 64 + lane];
            sr += ldsRed[((wp * 4 + w) * 3 + 1) * 64 + lane];
            f32x4 v2 = ldsRed[((wp * 4 + w) * 3 + 2) * 64 + lane];
            if (xw) sxh += v2; else srh += v2;
        }

        // ---- 4. gating + publish h_s (all 4 waves, 4 rows each)
        ushort_t* slabW = hxOwn + (size_t)(s & (R - 1)) * SLAB;
#pragma unroll
        for (int j = 0; j < 4; ++j) {
            const float z  = sigmf(sz[j] + bzz);
            const float r  = sigmf(sr[j] + brr);
            const float hh = tanhfast(sxh[j] + bxh + r * (srh[j] + brh));
            const float hn = z * hcur[j] + (1.f - z) * hh;
            hcur[j] = hn;
            const float hn2 = __shfl_xor(hn, 1);
            if ((lane & 1) == 0) {
                const unsigned pk = (unsigned)f2bf(hn) | ((unsigned)f2bf(hn2) << 16);
                const size_t e = ((size_t)(u_ >> 3) * 64 + (rowBase + j)) * 8 + (u_ & 7);
                __hip_atomic_store((unsigned*)slabW + (e >> 1), pk,
                                   __ATOMIC_RELAXED, __HIP_MEMORY_SCOPE_AGENT);
            }
        }

        // ---- 5. drain (syncthreads waits each thread's own vmcnt), flag
        __syncthreads();
        if (tid == 0)
            __hip_atomic_store(flags + layer * 64 + lwg, (unsigned)(s + 1),
                               __ATOMIC_RELAXED, __HIP_MEMORY_SCOPE_AGENT);
    }

    if (Hf != nullptr) {
#pragma unroll
        for (int j = 0; j < 4; ++j)
            Hf[(size_t)(rowBase + j) * 1024 + u_] = hcur[j];
    }
}

// ---------------------------------------------------------------------------
// fused 3-layer pipelined GRU. grid = 256 WGs; role = f(blockIdx%8) so each
// layer's 64 WGs land on one XCD pair under round-robin dispatch:
//   slots {0,1}->L0, {2,3}->L1, {4,5}->L2, {6,7} exit immediately.
// lwg = rep*2 + (slot&1), rep = blockIdx/8 in [0,32).
// ---------------------------------------------------------------------------
__global__ __launch_bounds__(256, 1) void gru_fused(
    const int* __restrict__ tokens, const ushort_t* __restrict__ embBN,
    const ushort_t* __restrict__ WkT0, const ushort_t* __restrict__ WkT1,
    const ushort_t* __restrict__ WkT2,
    const ushort_t* __restrict__ WrT0, const ushort_t* __restrict__ WrT1,
    const ushort_t* __restrict__ WrT2,
    const float* __restrict__ gb0, const float* __restrict__ gb1,
    const float* __restrict__ gb2,
    ushort_t* __restrict__ Hx, float* __restrict__ Hf,
    unsigned* __restrict__ flags, int R)
{
    __shared__ f32x4 ldsRed[3072];            // 48 KB: 4 waves x 4 rt x 3 g x 64 lanes
    const int slot = blockIdx.x & 7;
    const int rep  = blockIdx.x >> 3;         // 0..31
    const int layer = slot >> 1;              // 0..3
    if (layer >= 3) return;                   // slots 6,7: idle (before any barrier)
    const int lwg = rep * 2 + (slot & 1);     // 0..63
    ushort_t* hxL = Hx + (size_t)layer * R * SLAB;
    const ushort_t* hxP = (layer > 0) ? (Hx + (size_t)(layer - 1) * R * SLAB) : nullptr;

    if (layer == 0)
        gru_run<8,  true >(tokens, embBN, WkT0, WrT0, gb0, hxL, nullptr, nullptr,
                           flags, 0, lwg, R, ldsRed);
    else if (layer == 1)
        gru_run<32, false>(nullptr, nullptr, WkT1, WrT1, gb1, hxL, hxP, nullptr,
                           flags, 1, lwg, R, ldsRed);
    else
        gru_run<32, false>(nullptr, nullptr, WkT2, WrT2, gb2, hxL, hxP, Hf,
                           flags, 2, lwg, R, ldsRed);
}

// ---------------------------------------------------------------------------
// dense + softmax (verified). One WG per (b,f).
// ---------------------------------------------------------------------------
__global__ __launch_bounds__(256, 1) void dense_softmax(
    const float* __restrict__ hfinal, const float* __restrict__ Wd,
    const float* __restrict__ bd, float* __restrict__ out)
{
    const int tid = threadIdx.x;
    const int bf = blockIdx.x;
    __shared__ float sv[256];
    __shared__ float red[256];
    sv[tid] = hfinal[bf * 256 + tid];
    __syncthreads();
    float a0 = bd[tid], a1 = bd[tid + 256];
    for (int d = 0; d < 256; ++d) {
        float s = sv[d];
        a0 = fmaf(s, Wd[d * 512 + tid], a0);
        a1 = fmaf(s, Wd[d * 512 + tid + 256], a1);
    }
    red[tid] = fmaxf(a0, a1);
    __syncthreads();
    for (int st = 128; st > 0; st >>= 1) {
        if (tid < st) red[tid] = fmaxf(red[tid], red[tid + st]);
        __syncthreads();
    }
    const float mx = red[0];
    __syncthreads();
    float e0 = __expf(a0 - mx), e1 = __expf(a1 - mx);
    red[tid] = e0 + e1;
    __syncthreads();
    for (int st = 128; st > 0; st >>= 1) {
        if (tid < st) red[tid] += red[tid + st];
        __syncthreads();
    }
    const float inv = 1.f / red[0];
    out[(size_t)bf * 512 + tid] = e0 * inv;
    out[(size_t)bf * 512 + tid + 256] = e1 * inv;
}

// ---------------------------------------------------------------------------
extern "C" void kernel_launch(void* const* d_in, const int* in_sizes, int n_in,
                              void* d_out, int out_size, void* d_ws, size_t ws_size,
                              hipStream_t stream)
{
    (void)in_sizes; (void)n_in; (void)out_size;

    const int*   tokens = (const int*)d_in[0];
    const float* emb    = (const float*)d_in[1];
    const float* gamma  = (const float*)d_in[2];
    const float* beta   = (const float*)d_in[3];
    const float* mean   = (const float*)d_in[4];
    const float* var    = (const float*)d_in[5];
    const float* gk[3]  = {(const float*)d_in[6], (const float*)d_in[9],  (const float*)d_in[12]};
    const float* gr[3]  = {(const float*)d_in[7], (const float*)d_in[10], (const float*)d_in[13]};
    const float* gbb[3] = {(const float*)d_in[8], (const float*)d_in[11], (const float*)d_in[14]};
    const float* dw  = (const float*)d_in[15];
    const float* db  = (const float*)d_in[16];

    // workspace carve: fixed part ~33.6 MB, Hx ring takes the rest
    char* p = (char*)d_ws;
    ushort_t* WkT0  = (ushort_t*)p; p += (size_t)3072 * 256 * 2;
    ushort_t* WkT1  = (ushort_t*)p; p += (size_t)3072 * 1024 * 2;
    ushort_t* WkT2  = (ushort_t*)p; p += (size_t)3072 * 1024 * 2;
    ushort_t* WrTb[3];
    for (int l = 0; l < 3; ++l) { WrTb[l] = (ushort_t*)p; p += (size_t)3072 * 1024 * 2; }
    ushort_t* embBN = (ushort_t*)p; p += (size_t)512 * 256 * 2;
    float*    Hf    = (float*)p;    p += (size_t)64 * 1024 * 4;
    unsigned* flags = (unsigned*)p; p += 4096;
    ushort_t* Hx    = (ushort_t*)p;
    const size_t rem = ws_size - (size_t)(p - (char*)d_ws);
    // R=512: no address reuse, no epoch fences needed. Else R=256 ring (134 MB total).
    const int R = (rem >= (size_t)3 * 512 * SLAB * 2) ? 512 : 256;

    // MUST zero every launch: 0xAA ws poison would satisfy every flag poll.
    hipMemsetAsync(flags, 0, 4096, stream);

    pack_w<<<dim3(4, 48),  256, 0, stream>>>(gk[0], WkT0, 256);
    pack_w<<<dim3(16, 48), 256, 0, stream>>>(gk[1], WkT1, 1024);
    pack_w<<<dim3(16, 48), 256, 0, stream>>>(gk[2], WkT2, 1024);
    for (int l = 0; l < 3; ++l)
        pack_w<<<dim3(16, 48), 256, 0, stream>>>(gr[l], WrTb[l], 1024);

    embed_bn<<<512, 256, 0, stream>>>(emb, gamma, beta, mean, var, embBN);

    gru_fused<<<256, 256, 0, stream>>>(
        tokens, embBN, WkT0, WkT1, WkT2,
        WrTb[0], WrTb[1], WrTb[2], gbb[0], gbb[1], gbb[2],
        Hx, Hf, flags, R);

    dense_softmax<<<256, 256, 0, stream>>>(Hf, dw, db, (float*)d_out);
}

// Round 3
// 3860.412 us; speedup vs baseline: 2.6455x; 2.6455x over previous
//
#include <hip/hip_runtime.h>

// ---------------------------------------------------------------------------
// Teacher_model_7464653160858: embed+BN -> 3x GRU(1024, reset_after) -> dense+softmax
// B=64, T=512, E=256, U=1024, V=512.
//
// R6: 8-WAVE WGs + PER-WAVE DEPENDENCY POLLS. R5 post-mortem: FETCH dropped
// 3.8x (XCD placement works) but time flat -> step is a latency chain, not
// BW. Three chain-insertions vs R3's verified 7.2us skeleton, all removed:
//  1) VGPR_Count=184 < 192 needed for wf[16][3] -> weights were being
//     re-loaded from L2 every step inside the MFMA chain. Now 512-thr WGs,
//     8 waves, 8 kc/wave -> 96 VGPR weights, truly register-resident
//     (__launch_bounds__(512,2), ~210 VGPR < 256 cap).
//  2) x-part (prev-layer slab) loads were post-poll. Now x-waves (w<4) poll
//     ONLY prvT (satisfied early via pipeline skew) and run loads+MFMA while
//     h-waves (w>=4) poll ownT -- x work leaves the critical chain.
//  3) Single wave0 poll serialized everything. Now per-wave polls, waves
//     meet at the reduce barrier. 2 barriers/step, no top barrier.
//  - Everything else from R5 kept: flag protocol (monotonic, relaxed-atomic,
//    memset 0 per launch), sc-store/plain-read slabs, XCD-pair placement
//    (slot=blockIdx%8: {0,1}->L0 {2,3}->L1 {4,5}->L2, {6,7} exit),
//    adaptive ring R=512/256 with epoch __threadfence at s==256/511.
// ---------------------------------------------------------------------------

typedef short bf16x8 __attribute__((ext_vector_type(8)));
typedef float f32x4 __attribute__((ext_vector_type(4)));
typedef float f32x2 __attribute__((ext_vector_type(2)));
typedef unsigned short ushort_t;

#define MFMA16(a, b, c) __builtin_amdgcn_mfma_f32_16x16x32_bf16((a), (b), (c), 0, 0, 0)

#define SLAB 65536        // elems per h slab: 128 u8-groups * 64 b * 8 (128 KB)

__device__ __forceinline__ float bf2f(ushort_t h) {
    return __uint_as_float(((unsigned)h) << 16);
}
__device__ __forceinline__ ushort_t f2bf(float f) {
    unsigned u = __float_as_uint(f);
    u += 0x7FFFu + ((u >> 16) & 1u);   // RNE
    return (ushort_t)(u >> 16);
}
__device__ __forceinline__ float sigmf(float x) { return 1.f / (1.f + __expf(-x)); }
__device__ __forceinline__ float tanhfast(float x) {
    float e = __expf(2.f * x);
    return 1.f - 2.f / (e + 1.f);
}

// ---------------------------------------------------------------------------
// pack: W[K][3072] fp32 -> WT[3072][K] bf16 (transpose). grid (K/64, 48).
// ---------------------------------------------------------------------------
__global__ __launch_bounds__(256, 1) void pack_w(
    const float* __restrict__ W, ushort_t* __restrict__ WT, int K)
{
    __shared__ ushort_t tile[64][72];
    const int kt0 = blockIdx.x * 64;
    const int ct0 = blockIdx.y * 64;
    const int tx = threadIdx.x & 63;
    const int ty = threadIdx.x >> 6;
#pragma unroll
    for (int i = 0; i < 16; ++i) {
        int k = kt0 + ty * 16 + i;
        tile[ty * 16 + i][tx] = f2bf(W[(size_t)k * 3072 + ct0 + tx]);
    }
    __syncthreads();
#pragma unroll
    for (int i = 0; i < 16; ++i) {
        int c = ct0 + ty * 16 + i;
        WT[(size_t)c * K + kt0 + tx] = tile[tx][ty * 16 + i];
    }
}

// ---------------------------------------------------------------------------
// BN-folded embedding table (512x256 bf16)
// ---------------------------------------------------------------------------
__global__ __launch_bounds__(256, 1) void embed_bn(
    const float* __restrict__ emb,
    const float* __restrict__ gamma, const float* __restrict__ beta,
    const float* __restrict__ mean, const float* __restrict__ var,
    ushort_t* __restrict__ embBN)
{
    const int idx = blockIdx.x * 256 + threadIdx.x;
    const int e = idx & 255;
    const float sc = gamma[e] * rsqrtf(var[e] + 1e-3f);
    const float sh = beta[e] - mean[e] * sc;
    embBN[idx] = f2bf(fmaf(emb[idx], sc, sh));
}

// ---------------------------------------------------------------------------
// gru_run: one GRU layer, 64 WGs x 512 thr (8 waves), 512 steps.
// Wave roles (K-split over x-part + h-part, 8 kc of K=32 each for L1/2):
//   XKC=8  (L0): w0 = x (8 kc, embBN gather); w1..w7 = h {5,5,5,5,4,4,4} kc
//   XKC=32 (L1/2): w0..w3 = x (prev slab, kc w*8..); w4..w7 = h (own slab)
// x-waves poll prvT only; h-waves poll ownT (+ back-pressure). Reduce via
// LDS (96KB), gating rows w*8..w*8+7 per wave.
// ---------------------------------------------------------------------------
template<int XKC, bool EMB>
__device__ __forceinline__ void gru_run(
    const int* __restrict__ tokens,
    const ushort_t* __restrict__ embBN,
    const ushort_t* __restrict__ WkT,      // [3072][XKC*32]
    const ushort_t* __restrict__ WrT,      // [3072][1024]
    const float* __restrict__ gb,          // [2][3072] flat
    ushort_t* __restrict__ hxOwn,          // own slab ring base
    const ushort_t* __restrict__ hxPrev,   // prev-layer ring base (null if EMB)
    float* __restrict__ Hf,                // non-null on last layer only
    unsigned* __restrict__ flags,          // [3*64]
    const int layer, const int lwg, const int R,
    f32x4* __restrict__ ldsRed)            // [8][4][3][64]
{
    const int tid  = threadIdx.x;
    const int lane = tid & 63;
    const int w    = tid >> 6;             // 0..7
    const int n    = lane & 15, quad = lane >> 4;
    const int u_   = lwg * 16 + n;

    bool ISX; int CNT, BASE;
    if (XKC == 8) {
        ISX = (w == 0);
        if (w == 0)      { CNT = 8; BASE = 0; }
        else if (w <= 4) { CNT = 5; BASE = (w - 1) * 5; }
        else             { CNT = 4; BASE = 20 + (w - 5) * 4; }
    } else {
        ISX = (w < 4);
        CNT = 8; BASE = (w & 3) * 8;
    }
    const int KROW = ISX ? (EMB ? 256 : 1024) : 1024;
    const ushort_t* WT = ISX ? WkT : WrT;

    // once per dispatch: drop stale/poisoned L2 lines from prior launches
    __threadfence();

    // ---- preload weight B-fragments to registers (static-indexed, <=96 VGPR)
    bf16x8 wf[8][3];
#pragma unroll
    for (int i = 0; i < 8; ++i)
        if (i < CNT) {
            const int kc = BASE + i;
#pragma unroll
            for (int g = 0; g < 3; ++g)
                wf[i][g] = *(const bf16x8*)(WT + (size_t)(g * 1024 + u_) * KROW
                                            + kc * 32 + quad * 8);
        }

    const float bzz = gb[u_]        + gb[3072 + u_];
    const float brr = gb[1024 + u_] + gb[4096 + u_];
    const float bxh = gb[2048 + u_];
    const float brh = gb[5120 + u_];

    // gating rows for this wave: r0 = w*8 + (lane>>4)*2, r0+1
    const int g16  = lane >> 4;
    const int myrt = w >> 1;
    const int q    = (w & 1) * 2 + (g16 >> 1);
    const int reg0 = (g16 & 1) * 2;
    const int r0   = w * 8 + g16 * 2;
    const int off  = q * 16 + n;
    float hcur0 = 0.f, hcur1 = 0.f;

    for (int s = 0; s < 512; ++s) {
        // epoch fence: drop L2 copies of ring addresses about to be re-read
        if (R == 256 && (s == 256 || s == 511)) __threadfence();

        // ---- 1. per-wave dependency polls
        if (!ISX) {
            if (s > 0) {
                const unsigned ownT = (unsigned)s;
                const unsigned nxtT = (layer < 2 && s >= R) ? (unsigned)(s - R + 1) : 0u;
                const unsigned* fO = flags + layer * 64 + lane;
                const unsigned* fN = flags + (layer + 1) * 64 + lane;
                while (true) {
                    bool ok = (__ballot(__hip_atomic_load(fO, __ATOMIC_RELAXED,
                                 __HIP_MEMORY_SCOPE_AGENT) >= ownT) == ~0ull);
                    if (ok && nxtT)
                        ok = (__ballot(__hip_atomic_load(fN, __ATOMIC_RELAXED,
                                 __HIP_MEMORY_SCOPE_AGENT) >= nxtT) == ~0ull);
                    if (ok) break;
                    __builtin_amdgcn_s_sleep(1);
                }
            }
        } else if (!EMB) {
            const unsigned prvT = (unsigned)(s + 1);
            const unsigned* fP = flags + (layer - 1) * 64 + lane;
            while (__ballot(__hip_atomic_load(fP, __ATOMIC_RELAXED,
                     __HIP_MEMORY_SCOPE_AGENT) >= prvT) != ~0ull)
                __builtin_amdgcn_s_sleep(1);
        }
        asm volatile("" ::: "memory");        // no load hoisting above the poll

        // ---- 2. MFMA: this wave's K-slice (weights in regs, A from slabs)
        f32x4 acc[4][3] = {};
        if (ISX) {
            if (EMB) {
                int tk[4];
#pragma unroll
                for (int rt = 0; rt < 4; ++rt)
                    tk[rt] = tokens[(rt * 16 + n) * 512 + s] * 256;
#pragma unroll
                for (int i = 0; i < 8; ++i)
                    if (i < CNT) {
                        const int kc = BASE + i;
                        bf16x8 a[4];
#pragma unroll
                        for (int rt = 0; rt < 4; ++rt)
                            a[rt] = *(const bf16x8*)(embBN + (size_t)tk[rt]
                                                     + kc * 32 + quad * 8);
#pragma unroll
                        for (int rt = 0; rt < 4; ++rt)
#pragma unroll
                            for (int g = 0; g < 3; ++g)
                                acc[rt][g] = MFMA16(a[rt], wf[i][g], acc[rt][g]);
                    }
            } else {
                const ushort_t* sp = hxPrev + (size_t)(s & (R - 1)) * SLAB;
#pragma unroll
                for (int i = 0; i < 8; ++i)
                    if (i < CNT) {
                        const int kc = BASE + i;
                        bf16x8 a[4];
#pragma unroll
                        for (int rt = 0; rt < 4; ++rt)
                            a[rt] = *(const bf16x8*)(sp +
                                     ((kc * 4 + quad) * 64 + rt * 16 + n) * 8);
#pragma unroll
                        for (int rt = 0; rt < 4; ++rt)
#pragma unroll
                            for (int g = 0; g < 3; ++g)
                                acc[rt][g] = MFMA16(a[rt], wf[i][g], acc[rt][g]);
                    }
            }
        } else if (s > 0) {                   // h_0 = 0: skip at s==0
            const ushort_t* so = hxOwn + (size_t)((s - 1) & (R - 1)) * SLAB;
#pragma unroll
            for (int i = 0; i < 8; ++i)
                if (i < CNT) {
                    const int kc = BASE + i;
                    bf16x8 a[4];
#pragma unroll
                    for (int rt = 0; rt < 4; ++rt)
                        a[rt] = *(const bf16x8*)(so +
                                 ((kc * 4 + quad) * 64 + rt * 16 + n) * 8);
#pragma unroll
                    for (int rt = 0; rt < 4; ++rt)
#pragma unroll
                        for (int g = 0; g < 3; ++g)
                            acc[rt][g] = MFMA16(a[rt], wf[i][g], acc[rt][g]);
                }
        }

        // ---- 3. cross-wave K-reduce staging
#pragma unroll
        for (int rt = 0; rt < 4; ++rt)
#pragma unroll
            for (int g = 0; g < 3; ++g)
                ldsRed[((w * 4 + rt) * 3 + g) * 64 + lane] = acc[rt][g];
        __syncthreads();                      // B1: red ready

        // ---- 4. reduce + gate rows r0, r0+1 (all 8 waves)
        const float* ldsF = (const float*)ldsRed;
        float sz0 = 0.f, sz1 = 0.f, sr0 = 0.f, sr1 = 0.f;
        float sxh0 = 0.f, sxh1 = 0.f, srh0 = 0.f, srh1 = 0.f;
#pragma unroll
        for (int wp = 0; wp < 8; ++wp) {
            const bool xw = (XKC == 8) ? (wp == 0) : (wp < 4);
            const int tb = (wp * 4 + myrt) * 3;
            f32x2 vz = *(const f32x2*)(ldsF + ((size_t)(tb + 0) * 64 + off) * 4 + reg0);
            f32x2 vr = *(const f32x2*)(ldsF + ((size_t)(tb + 1) * 64 + off) * 4 + reg0);
            f32x2 vh = *(const f32x2*)(ldsF + ((size_t)(tb + 2) * 64 + off) * 4 + reg0);
            sz0 += vz[0]; sz1 += vz[1];
            sr0 += vr[0]; sr1 += vr[1];
            if (xw) { sxh0 += vh[0]; sxh1 += vh[1]; }
            else    { srh0 += vh[0]; srh1 += vh[1]; }
        }
        float hn0, hn1;
        {
            const float z  = sigmf(sz0 + bzz);
            const float r  = sigmf(sr0 + brr);
            const float hh = tanhfast(sxh0 + bxh + r * (srh0 + brh));
            hn0 = z * hcur0 + (1.f - z) * hh; hcur0 = hn0;
        }
        {
            const float z  = sigmf(sz1 + bzz);
            const float r  = sigmf(sr1 + brr);
            const float hh = tanhfast(sxh1 + bxh + r * (srh1 + brh));
            hn1 = z * hcur1 + (1.f - z) * hh; hcur1 = hn1;
        }

        // ---- 5. publish h_s (pack u-pairs via shfl, even lanes store dwords)
        {
            ushort_t* sw = hxOwn + (size_t)(s & (R - 1)) * SLAB;
            const float p0 = __shfl_xor(hn0, 1);
            const float p1 = __shfl_xor(hn1, 1);
            if ((lane & 1) == 0) {
                const unsigned pk0 = (unsigned)f2bf(hn0) | ((unsigned)f2bf(p0) << 16);
                const unsigned pk1 = (unsigned)f2bf(hn1) | ((unsigned)f2bf(p1) << 16);
                const size_t e0 = ((size_t)(u_ >> 3) * 64 + r0) * 8 + (u_ & 7);
                const size_t e1 = ((size_t)(u_ >> 3) * 64 + r0 + 1) * 8 + (u_ & 7);
                __hip_atomic_store((unsigned*)sw + (e0 >> 1), pk0,
                                   __ATOMIC_RELAXED, __HIP_MEMORY_SCOPE_AGENT);
                __hip_atomic_store((unsigned*)sw + (e1 >> 1), pk1,
                                   __ATOMIC_RELAXED, __HIP_MEMORY_SCOPE_AGENT);
            }
        }

        // ---- 6. drain (syncthreads waits each thread's own vmcnt) then flag
        __syncthreads();                      // B2: drained + red consumed
        if (tid == 0)
            __hip_atomic_store(flags + layer * 64 + lwg, (unsigned)(s + 1),
                               __ATOMIC_RELAXED, __HIP_MEMORY_SCOPE_AGENT);
    }

    if (Hf != nullptr) {
        Hf[(size_t)r0 * 1024 + u_]       = hcur0;
        Hf[(size_t)(r0 + 1) * 1024 + u_] = hcur1;
    }
}

// ---------------------------------------------------------------------------
// fused 3-layer pipelined GRU. grid = 256 WGs x 512 thr; XCD slot mapping:
// slots {0,1}->L0, {2,3}->L1, {4,5}->L2, {6,7} exit. lwg = rep*2+(slot&1).
// ---------------------------------------------------------------------------
__global__ __launch_bounds__(512, 2) void gru_fused(
    const int* __restrict__ tokens, const ushort_t* __restrict__ embBN,
    const ushort_t* __restrict__ WkT0, const ushort_t* __restrict__ WkT1,
    const ushort_t* __restrict__ WkT2,
    const ushort_t* __restrict__ WrT0, const ushort_t* __restrict__ WrT1,
    const ushort_t* __restrict__ WrT2,
    const float* __restrict__ gb0, const float* __restrict__ gb1,
    const float* __restrict__ gb2,
    ushort_t* __restrict__ Hx, float* __restrict__ Hf,
    unsigned* __restrict__ flags, int R)
{
    __shared__ f32x4 ldsRed[6144];            // 96 KB: 8 waves x 4 rt x 3 g x 64
    const int slot = blockIdx.x & 7;
    const int rep  = blockIdx.x >> 3;         // 0..31
    const int layer = slot >> 1;
    if (layer >= 3) return;                   // slots 6,7: idle
    const int lwg = rep * 2 + (slot & 1);     // 0..63
    ushort_t* hxL = Hx + (size_t)layer * R * SLAB;
    const ushort_t* hxP = (layer > 0) ? (Hx + (size_t)(layer - 1) * R * SLAB) : nullptr;

    if (layer == 0)
        gru_run<8,  true >(tokens, embBN, WkT0, WrT0, gb0, hxL, nullptr, nullptr,
                           flags, 0, lwg, R, ldsRed);
    else if (layer == 1)
        gru_run<32, false>(nullptr, nullptr, WkT1, WrT1, gb1, hxL, hxP, nullptr,
                           flags, 1, lwg, R, ldsRed);
    else
        gru_run<32, false>(nullptr, nullptr, WkT2, WrT2, gb2, hxL, hxP, Hf,
                           flags, 2, lwg, R, ldsRed);
}

// ---------------------------------------------------------------------------
// dense + softmax (verified). One WG per (b,f).
// ---------------------------------------------------------------------------
__global__ __launch_bounds__(256, 1) void dense_softmax(
    const float* __restrict__ hfinal, const float* __restrict__ Wd,
    const float* __restrict__ bd, float* __restrict__ out)
{
    const int tid = threadIdx.x;
    const int bf = blockIdx.x;
    __shared__ float sv[256];
    __shared__ float red[256];
    sv[tid] = hfinal[bf * 256 + tid];
    __syncthreads();
    float a0 = bd[tid], a1 = bd[tid + 256];
    for (int d = 0; d < 256; ++d) {
        float s = sv[d];
        a0 = fmaf(s, Wd[d * 512 + tid], a0);
        a1 = fmaf(s, Wd[d * 512 + tid + 256], a1);
    }
    red[tid] = fmaxf(a0, a1);
    __syncthreads();
    for (int st = 128; st > 0; st >>= 1) {
        if (tid < st) red[tid] = fmaxf(red[tid], red[tid + st]);
        __syncthreads();
    }
    const float mx = red[0];
    __syncthreads();
    float e0 = __expf(a0 - mx), e1 = __expf(a1 - mx);
    red[tid] = e0 + e1;
    __syncthreads();
    for (int st = 128; st > 0; st >>= 1) {
        if (tid < st) red[tid] += red[tid + st];
        __syncthreads();
    }
    const float inv = 1.f / red[0];
    out[(size_t)bf * 512 + tid] = e0 * inv;
    out[(size_t)bf * 512 + tid + 256] = e1 * inv;
}

// ---------------------------------------------------------------------------
extern "C" void kernel_launch(void* const* d_in, const int* in_sizes, int n_in,
                              void* d_out, int out_size, void* d_ws, size_t ws_size,
                              hipStream_t stream)
{
    (void)in_sizes; (void)n_in; (void)out_size;

    const int*   tokens = (const int*)d_in[0];
    const float* emb    = (const float*)d_in[1];
    const float* gamma  = (const float*)d_in[2];
    const float* beta   = (const float*)d_in[3];
    const float* mean   = (const float*)d_in[4];
    const float* var    = (const float*)d_in[5];
    const float* gk[3]  = {(const float*)d_in[6], (const float*)d_in[9],  (const float*)d_in[12]};
    const float* gr[3]  = {(const float*)d_in[7], (const float*)d_in[10], (const float*)d_in[13]};
    const float* gbb[3] = {(const float*)d_in[8], (const float*)d_in[11], (const float*)d_in[14]};
    const float* dw  = (const float*)d_in[15];
    const float* db  = (const float*)d_in[16];

    // workspace carve: fixed part ~33.6 MB, Hx ring takes the rest
    char* p = (char*)d_ws;
    ushort_t* WkT0  = (ushort_t*)p; p += (size_t)3072 * 256 * 2;
    ushort_t* WkT1  = (ushort_t*)p; p += (size_t)3072 * 1024 * 2;
    ushort_t* WkT2  = (ushort_t*)p; p += (size_t)3072 * 1024 * 2;
    ushort_t* WrTb[3];
    for (int l = 0; l < 3; ++l) { WrTb[l] = (ushort_t*)p; p += (size_t)3072 * 1024 * 2; }
    ushort_t* embBN = (ushort_t*)p; p += (size_t)512 * 256 * 2;
    float*    Hf    = (float*)p;    p += (size_t)64 * 1024 * 4;
    unsigned* flags = (unsigned*)p; p += 4096;
    ushort_t* Hx    = (ushort_t*)p;
    const size_t rem = ws_size - (size_t)(p - (char*)d_ws);
    // R=512: no address reuse, no epoch fences needed. Else R=256 ring.
    const int R = (rem >= (size_t)3 * 512 * SLAB * 2) ? 512 : 256;

    // MUST zero every launch: 0xAA ws poison would satisfy every flag poll.
    hipMemsetAsync(flags, 0, 4096, stream);

    pack_w<<<dim3(4, 48),  256, 0, stream>>>(gk[0], WkT0, 256);
    pack_w<<<dim3(16, 48), 256, 0, stream>>>(gk[1], WkT1, 1024);
    pack_w<<<dim3(16, 48), 256, 0, stream>>>(gk[2], WkT2, 1024);
    for (int l = 0; l < 3; ++l)
        pack_w<<<dim3(16, 48), 256, 0, stream>>>(gr[l], WrTb[l], 1024);

    embed_bn<<<512, 256, 0, stream>>>(emb, gamma, beta, mean, var, embBN);

    gru_fused<<<256, 512, 0, stream>>>(
        tokens, embBN, WkT0, WkT1, WkT2,
        WrTb[0], WrTb[1], WrTb[2], gbb[0], gbb[1], gbb[2],
        Hx, Hf, flags, R);

    dense_softmax<<<256, 256, 0, stream>>>(Hf, dw, db, (float*)d_out);
}